// Round 1
// baseline (3830.329 us; speedup 1.0000x reference)
//
#include <hip/hip_runtime.h>

// LSTM predictor: B=2048 rows, T=2048 steps + 128 future, H=51.
// One block (4 waves) per batch row. Wave g owns gate block g (PyTorch order
// i,f,g,o). Lane k of wave g owns gate row g*51+k with W_hh row in VGPRs.
// h is kept redundantly per-wave (lane k holds h_k) and broadcast via a
// per-wave LDS copy read with uniform-address float4 loads.
// One __syncthreads per step (double-buffered gate exchange).

constexpr int Hh = 51;

__device__ __forceinline__ float fexp2(float x) { return __builtin_amdgcn_exp2f(x); }
__device__ __forceinline__ float frcp(float x)  { return __builtin_amdgcn_rcpf(x); }
// sigmoid(x) = 1/(1+2^(-x*log2e))
__device__ __forceinline__ float sigm(float x)  { return frcp(1.f + fexp2(-1.44269504f * x)); }
// tanh(x) = 1 - 2/(1+2^(2x*log2e)); saturates correctly at +-inf
__device__ __forceinline__ float tanh_f(float x){ return 1.f - 2.f * frcp(1.f + fexp2(2.88539008f * x)); }

__device__ __forceinline__ float rdlane(float v, int lane) {
  return __int_as_float(__builtin_amdgcn_readlane(__float_as_int(v), lane));
}

__global__ void lstm_kernel(const float* __restrict__ x,
                            const float* __restrict__ W_ih,
                            const float* __restrict__ W_hh,
                            const float* __restrict__ b_ih,
                            const float* __restrict__ b_hh,
                            const float* __restrict__ fc_w,
                            const float* __restrict__ fc_b,
                            float* __restrict__ out,
                            int T, int OT)
{
  const int b   = blockIdx.x;
  const int tid = threadIdx.x;
  const int g   = tid >> 6;   // wave id = gate block (0:i 1:f 2:g 3:o)
  const int k   = tid & 63;   // lane

  __shared__ __align__(16) float hbuf[4][52];     // per-wave h copy, [51] = 0 pad
  __shared__ __align__(16) float gl[2][52][4];    // double-buffered gate exchange

  if (k < 52) hbuf[g][k] = 0.f;

  // ---- load weights into registers (one-time; W is tiny and L1/L2 cached)
  float w[51];
  float wih = 0.f, bsum = 0.f, fcw = 0.f;
  const int row = g * Hh + k;
  if (k < Hh) {
#pragma unroll
    for (int j = 0; j < Hh; ++j) w[j] = W_hh[row * Hh + j];
    wih  = W_ih[row];
    bsum = b_ih[row] + b_hh[row];
    fcw  = fc_w[k];
  }
  const float fcb = fc_b[0];

  float c = 0.f, h = 0.f;
  float out_prev = 0.f;
  float xv = 0.f;
  float xv_next = x[(long)b * T + k];   // chunk 0 prefetch (T is a multiple of 64)

  __syncthreads();

  for (int t = 0; t < OT; ++t) {
    // ---- input for this step (uniform across all lanes/waves)
    float xt;
    if (t < T) {
      if ((t & 63) == 0) {
        xv = xv_next;
        if (t + 64 < T) xv_next = x[(long)b * T + t + 64 + k];
      }
      xt = rdlane(xv, t & 63);
    } else {
      xt = out_prev;
    }

    // ---- gate pre-activation: acc = x*W_ih + b + sum_j h_j * W_hh[row][j]
    float a0 = fmaf(xt, wih, bsum), a1 = 0.f, a2 = 0.f, a3 = 0.f;
    const float4* hb4 = (const float4*)(&hbuf[g][0]);
#pragma unroll
    for (int jj = 0; jj < 13; ++jj) {
      const float4 hv = hb4[jj];       // uniform-address broadcast read
      const int j0 = jj * 4;
      a0 = fmaf(hv.x, w[j0], a0);
      if (j0 + 1 < Hh) a1 = fmaf(hv.y, w[j0 + 1], a1);
      if (j0 + 2 < Hh) a2 = fmaf(hv.z, w[j0 + 2], a2);
      if (j0 + 3 < Hh) a3 = fmaf(hv.w, w[j0 + 3], a3);
    }
    const float acc = (a0 + a1) + (a2 + a3);

    // ---- own-gate nonlinearity, exchange across waves
    const float act = (g == 2) ? tanh_f(acc) : sigm(acc);
    const int buf = t & 1;
    if (k < Hh) gl[buf][k][g] = act;
    __syncthreads();

    // ---- redundant per-wave state update (keeps h wave-local, 1 barrier/step)
    float4 gv;
    if (k < Hh) gv = *(const float4*)(&gl[buf][k][0]);
    else        gv = make_float4(0.f, 0.f, 0.f, 0.f);
    c = fmaf(gv.y, c, gv.x * gv.z);    // c = f*c + i*g
    const float th = tanh_f(c);
    h = gv.w * th;                     // h = o*tanh(c)
    if (k < Hh) hbuf[g][k] = h;

    // ---- fc output: out_t = h . fc_w + fc_b (wave-wide reduce, all waves redundant)
    float p = (k < Hh) ? h * fcw : 0.f;
#pragma unroll
    for (int off = 32; off > 0; off >>= 1) p += __shfl_xor(p, off, 64);
    const float out_t = p + fcb;
    if (tid == 0) out[(long)b * OT + t] = out_t;
    out_prev = out_t;
  }
}

extern "C" void kernel_launch(void* const* d_in, const int* in_sizes, int n_in,
                              void* d_out, int out_size, void* d_ws, size_t ws_size,
                              hipStream_t stream) {
  const float* x    = (const float*)d_in[0];
  const float* W_ih = (const float*)d_in[1];
  const float* W_hh = (const float*)d_in[2];
  const float* b_ih = (const float*)d_in[3];
  const float* b_hh = (const float*)d_in[4];
  const float* fc_w = (const float*)d_in[5];
  const float* fc_b = (const float*)d_in[6];
  float* out = (float*)d_out;

  const int B  = 2048;
  const int T  = in_sizes[0] / B;   // 2048
  const int OT = out_size / B;      // 2176 = T + future

  lstm_kernel<<<dim3(B), dim3(256), 0, stream>>>(x, W_ih, W_hh, b_ih, b_hh,
                                                 fc_w, fc_b, out, T, OT);
}

// Round 2
// 2117.548 us; speedup vs baseline: 1.8089x; 1.8089x over previous
//
#include <hip/hip_runtime.h>

// LSTM predictor: B=2048 rows, T=2048 + 128 future, H=51.
// ONE WAVE per batch row (4 waves/block, grid 512). Lane k owns unit k and
// holds ALL FOUR W_hh gate rows in VGPRs (4*52=208 regs). h is broadcast via
// a per-wave LDS vector read with uniform-address float4 loads (conflict-free
// broadcast). No __syncthreads anywhere: same-wave DS ops are FIFO-ordered;
// asm memory clobbers stop the compiler from reordering across the h write.

constexpr int Hh = 51;

__device__ __forceinline__ float fexp2(float x) { return __builtin_amdgcn_exp2f(x); }
__device__ __forceinline__ float frcp(float x)  { return __builtin_amdgcn_rcpf(x); }
// sigmoid(x) = 1/(1+2^(-x*log2e))
__device__ __forceinline__ float sigm(float x)  { return frcp(1.f + fexp2(-1.44269504f * x)); }
// tanh(x) = 1 - 2/(1+2^(2x*log2e))
__device__ __forceinline__ float tanh_f(float x){ return 1.f - 2.f * frcp(1.f + fexp2(2.88539008f * x)); }

__device__ __forceinline__ float rdlane(float v, int lane) {
  return __int_as_float(__builtin_amdgcn_readlane(__float_as_int(v), lane));
}

__global__ __launch_bounds__(256, 2)
void lstm_kernel(const float* __restrict__ x,
                 const float* __restrict__ W_ih,
                 const float* __restrict__ W_hh,
                 const float* __restrict__ b_ih,
                 const float* __restrict__ b_hh,
                 const float* __restrict__ fc_w,
                 const float* __restrict__ fc_b,
                 float* __restrict__ out,
                 int T, int OT)
{
  const int wv  = threadIdx.x >> 6;          // wave in block
  const int k   = threadIdx.x & 63;          // lane = hidden unit
  const int row = blockIdx.x * 4 + wv;       // batch row

  __shared__ __align__(16) float hbuf[4][64];  // per-wave h vector, [51..63]=0
  hbuf[wv][k] = 0.f;
  asm volatile("" ::: "memory");

  // ---- all four gate rows of W_hh in registers (pad j=51 with 0)
  float w0[52], w1[52], w2[52], w3[52];
#pragma unroll
  for (int j = 0; j < 52; ++j) { w0[j] = w1[j] = w2[j] = w3[j] = 0.f; }
  float wi0 = 0.f, wi1 = 0.f, wi2 = 0.f, wi3 = 0.f;
  float bs0 = 0.f, bs1 = 0.f, bs2 = 0.f, bs3 = 0.f, fcw = 0.f;
  if (k < Hh) {
#pragma unroll
    for (int j = 0; j < Hh; ++j) {
      w0[j] = W_hh[(0 * Hh + k) * Hh + j];
      w1[j] = W_hh[(1 * Hh + k) * Hh + j];
      w2[j] = W_hh[(2 * Hh + k) * Hh + j];
      w3[j] = W_hh[(3 * Hh + k) * Hh + j];
    }
    wi0 = W_ih[0 * Hh + k]; wi1 = W_ih[1 * Hh + k];
    wi2 = W_ih[2 * Hh + k]; wi3 = W_ih[3 * Hh + k];
    bs0 = b_ih[0 * Hh + k] + b_hh[0 * Hh + k];
    bs1 = b_ih[1 * Hh + k] + b_hh[1 * Hh + k];
    bs2 = b_ih[2 * Hh + k] + b_hh[2 * Hh + k];
    bs3 = b_ih[3 * Hh + k] + b_hh[3 * Hh + k];
    fcw = fc_w[k];
  }
  const float fcb = fc_b[0];

  float c = 0.f, h = 0.f, out_prev = 0.f, obuf = 0.f;
  float xv = 0.f;
  float xv_next = x[(long)row * T + k];   // chunk 0 prefetch (T % 64 == 0)

  for (int t = 0; t < OT; ++t) {
    // ---- input (wave-uniform scalar)
    float xt;
    if (t < T) {
      if ((t & 63) == 0) {
        xv = xv_next;
        if (t + 64 < T) xv_next = x[(long)row * T + t + 64 + k];
      }
      xt = rdlane(xv, t & 63);
    } else {
      xt = out_prev;
    }

    // ---- four gate pre-activations (4 independent FMA chains)
    float a0 = fmaf(xt, wi0, bs0);
    float a1 = fmaf(xt, wi1, bs1);
    float a2 = fmaf(xt, wi2, bs2);
    float a3 = fmaf(xt, wi3, bs3);
    const float4* hb4 = (const float4*)(&hbuf[wv][0]);
#pragma unroll
    for (int jj = 0; jj < 13; ++jj) {
      const float4 hv = hb4[jj];     // uniform-address broadcast read
      const int j0 = jj * 4;
      a0 = fmaf(hv.x, w0[j0], a0); a0 = fmaf(hv.y, w0[j0+1], a0);
      a0 = fmaf(hv.z, w0[j0+2], a0); a0 = fmaf(hv.w, w0[j0+3], a0);
      a1 = fmaf(hv.x, w1[j0], a1); a1 = fmaf(hv.y, w1[j0+1], a1);
      a1 = fmaf(hv.z, w1[j0+2], a1); a1 = fmaf(hv.w, w1[j0+3], a1);
      a2 = fmaf(hv.x, w2[j0], a2); a2 = fmaf(hv.y, w2[j0+1], a2);
      a2 = fmaf(hv.z, w2[j0+2], a2); a2 = fmaf(hv.w, w2[j0+3], a2);
      a3 = fmaf(hv.x, w3[j0], a3); a3 = fmaf(hv.y, w3[j0+1], a3);
      a3 = fmaf(hv.z, w3[j0+2], a3); a3 = fmaf(hv.w, w3[j0+3], a3);
    }

    // ---- nonlinearities + state update (i,f,g,o order)
    const float ia = sigm(a0);
    const float fa = sigm(a1);
    const float ga = tanh_f(a2);
    const float oa = sigm(a3);
    c = fmaf(fa, c, ia * ga);
    h = oa * tanh_f(c);

    // ---- publish h for next step (wave-synchronous, no barrier)
    asm volatile("" ::: "memory");
    if (k < Hh) hbuf[wv][k] = h;
    asm volatile("" ::: "memory");

    // ---- fc output: out_t = h . fc_w + fc_b
    float p = (k < Hh) ? h * fcw : 0.f;
#pragma unroll
    for (int off = 32; off > 0; off >>= 1) p += __shfl_xor(p, off, 64);
    const float out_t = p + fcb;
    out_prev = out_t;
    obuf = (k == (t & 63)) ? out_t : obuf;   // stash in lane (t%64)
    if ((t & 63) == 63)                       // coalesced 64-wide store
      out[(long)row * OT + (t - 63) + k] = obuf;
  }
}

extern "C" void kernel_launch(void* const* d_in, const int* in_sizes, int n_in,
                              void* d_out, int out_size, void* d_ws, size_t ws_size,
                              hipStream_t stream) {
  const float* x    = (const float*)d_in[0];
  const float* W_ih = (const float*)d_in[1];
  const float* W_hh = (const float*)d_in[2];
  const float* b_ih = (const float*)d_in[3];
  const float* b_hh = (const float*)d_in[4];
  const float* fc_w = (const float*)d_in[5];
  const float* fc_b = (const float*)d_in[6];
  float* out = (float*)d_out;

  const int B  = 2048;
  const int T  = in_sizes[0] / B;   // 2048
  const int OT = out_size / B;      // 2176

  lstm_kernel<<<dim3(B / 4), dim3(256), 0, stream>>>(x, W_ih, W_hh, b_ih, b_hh,
                                                     fc_w, fc_b, out, T, OT);
}

// Round 3
// 1850.471 us; speedup vs baseline: 2.0699x; 1.1443x over previous
//
#include <hip/hip_runtime.h>

// LSTM predictor: B=2048 rows, T=2048 + 128 future, H=51.
// ONE WAVE per batch row, one wave per block (grid 2048). Lane k owns hidden
// unit k and holds all four W_hh gate rows (204 floats) in arch VGPRs.
// amdgpu_waves_per_eu(2,2) stops the allocator from chasing the 128-VGPR
// occupancy tier (round-2 failure mode: 124 VGPRs + AGPR spill of weights).
// h broadcast via per-block LDS vector (uniform-address float4 reads).
// fc output batched: per-step conflict-free ds_write of h*fcw, per-64-step
// transposed column-sum + coalesced store. No barriers (single wave).

constexpr int Hh = 51;

__device__ __forceinline__ float fexp2(float x) { return __builtin_amdgcn_exp2f(x); }
__device__ __forceinline__ float frcp(float x)  { return __builtin_amdgcn_rcpf(x); }
// sigmoid(x) = 1/(1+2^(-x*log2e))
__device__ __forceinline__ float sigm(float x)  { return frcp(1.f + fexp2(-1.44269504f * x)); }
// tanh(x) = 1 - 2/(1+2^(2x*log2e))
__device__ __forceinline__ float tanh_f(float x){ return 1.f - 2.f * frcp(1.f + fexp2(2.88539008f * x)); }

__device__ __forceinline__ float rdlane(float v, int lane) {
  return __int_as_float(__builtin_amdgcn_readlane(__float_as_int(v), lane));
}

__global__ __launch_bounds__(64)
__attribute__((amdgpu_waves_per_eu(2, 2)))
void lstm_kernel(const float* __restrict__ x,
                 const float* __restrict__ W_ih,
                 const float* __restrict__ W_hh,
                 const float* __restrict__ b_ih,
                 const float* __restrict__ b_hh,
                 const float* __restrict__ fc_w,
                 const float* __restrict__ fc_b,
                 float* __restrict__ out,
                 int T, int OT)
{
  const int k   = threadIdx.x;   // lane = hidden unit
  const int row = blockIdx.x;    // batch row

  __shared__ __align__(16) float hbuf[64];    // h vector; [51..63] junk-or-0, never used
  __shared__ float st[64][65];                // p stash: st[lane][step_in_chunk]

  hbuf[k] = 0.f;

  // ---- weights: unconditional loads with clamped row (no divergence).
  // Lanes 51..63 compute bounded junk; fcw=0 keeps them out of the output,
  // and they only ever write hbuf[k>=51], which the matvec never reads.
  const int kc = (k < Hh) ? k : (Hh - 1);
  float w0[Hh], w1[Hh], w2[Hh], w3[Hh];
#pragma unroll
  for (int j = 0; j < Hh; ++j) {
    w0[j] = W_hh[(0 * Hh + kc) * Hh + j];
    w1[j] = W_hh[(1 * Hh + kc) * Hh + j];
    w2[j] = W_hh[(2 * Hh + kc) * Hh + j];
    w3[j] = W_hh[(3 * Hh + kc) * Hh + j];
  }
  const float wi0 = W_ih[0 * Hh + kc], wi1 = W_ih[1 * Hh + kc];
  const float wi2 = W_ih[2 * Hh + kc], wi3 = W_ih[3 * Hh + kc];
  const float bs0 = b_ih[0 * Hh + kc] + b_hh[0 * Hh + kc];
  const float bs1 = b_ih[1 * Hh + kc] + b_hh[1 * Hh + kc];
  const float bs2 = b_ih[2 * Hh + kc] + b_hh[2 * Hh + kc];
  const float bs3 = b_ih[3 * Hh + kc] + b_hh[3 * Hh + kc];
  const float fcw = (k < Hh) ? fc_w[k] : 0.f;
  const float fcb = fc_b[0];

  float c = 0.f, h = 0.f;

  auto cell = [&](float xt) {
    float a0 = fmaf(xt, wi0, bs0);
    float a1 = fmaf(xt, wi1, bs1);
    float a2 = fmaf(xt, wi2, bs2);
    float a3 = fmaf(xt, wi3, bs3);
    const float4* hb4 = (const float4*)hbuf;
#pragma unroll
    for (int jj = 0; jj < 12; ++jj) {
      const float4 hv = hb4[jj];       // uniform-address broadcast read
      const int j0 = jj * 4;
      a0 = fmaf(hv.x, w0[j0], a0); a0 = fmaf(hv.y, w0[j0+1], a0);
      a0 = fmaf(hv.z, w0[j0+2], a0); a0 = fmaf(hv.w, w0[j0+3], a0);
      a1 = fmaf(hv.x, w1[j0], a1); a1 = fmaf(hv.y, w1[j0+1], a1);
      a1 = fmaf(hv.z, w1[j0+2], a1); a1 = fmaf(hv.w, w1[j0+3], a1);
      a2 = fmaf(hv.x, w2[j0], a2); a2 = fmaf(hv.y, w2[j0+1], a2);
      a2 = fmaf(hv.z, w2[j0+2], a2); a2 = fmaf(hv.w, w2[j0+3], a2);
      a3 = fmaf(hv.x, w3[j0], a3); a3 = fmaf(hv.y, w3[j0+1], a3);
      a3 = fmaf(hv.z, w3[j0+2], a3); a3 = fmaf(hv.w, w3[j0+3], a3);
    }
    {
      const float4 hv = hb4[12];       // tail: units 48..50
      a0 = fmaf(hv.x, w0[48], a0); a0 = fmaf(hv.y, w0[49], a0); a0 = fmaf(hv.z, w0[50], a0);
      a1 = fmaf(hv.x, w1[48], a1); a1 = fmaf(hv.y, w1[49], a1); a1 = fmaf(hv.z, w1[50], a1);
      a2 = fmaf(hv.x, w2[48], a2); a2 = fmaf(hv.y, w2[49], a2); a2 = fmaf(hv.z, w2[50], a2);
      a3 = fmaf(hv.x, w3[48], a3); a3 = fmaf(hv.y, w3[49], a3); a3 = fmaf(hv.z, w3[50], a3);
    }
    const float ia = sigm(a0);
    const float fa = sigm(a1);
    const float ga = tanh_f(a2);
    const float oa = sigm(a3);
    c = fmaf(fa, c, ia * ga);
    h = oa * tanh_f(c);
    asm volatile("" ::: "memory");
    hbuf[k] = h;                       // publish for next step (wave-synchronous)
    asm volatile("" ::: "memory");
  };

  // ---- main phase: T steps in chunks of 64
  float s = fcb;
  for (int tc = 0; tc < T; tc += 64) {
    const float xv = x[(long)row * T + tc + k];   // coalesced chunk load
#pragma unroll 1
    for (int i = 0; i < 64; ++i) {
      cell(rdlane(xv, i));
      st[k][i] = h * fcw;              // conflict-free (stride 65)
    }
    // transpose-reduce: lane t sums column t -> out[tc + t]
    s = fcb;
#pragma unroll
    for (int j = 0; j < 64; ++j) s += st[j][k];   // conflict-free per j
    asm volatile("" ::: "memory");
    out[(long)row * OT + tc + k] = s;  // coalesced store
  }

  // ---- future phase: feedback out -> x, butterfly reduce each step
  float out_prev = rdlane(s, 63);      // out[T-1]
  float obuf = 0.f;
  for (int t = T; t < OT; ++t) {
    cell(out_prev);
    float p = h * fcw;
#pragma unroll
    for (int off = 32; off > 0; off >>= 1) p += __shfl_xor(p, off, 64);
    const float out_t = p + fcb;
    obuf = (k == (t & 63)) ? out_t : obuf;
    if ((t & 63) == 63)
      out[(long)row * OT + (t - 63) + k] = obuf;  // coalesced
    out_prev = out_t;
  }
}

extern "C" void kernel_launch(void* const* d_in, const int* in_sizes, int n_in,
                              void* d_out, int out_size, void* d_ws, size_t ws_size,
                              hipStream_t stream) {
  const float* x    = (const float*)d_in[0];
  const float* W_ih = (const float*)d_in[1];
  const float* W_hh = (const float*)d_in[2];
  const float* b_ih = (const float*)d_in[3];
  const float* b_hh = (const float*)d_in[4];
  const float* fc_w = (const float*)d_in[5];
  const float* fc_b = (const float*)d_in[6];
  float* out = (float*)d_out;

  const int B  = 2048;
  const int T  = in_sizes[0] / B;   // 2048
  const int OT = out_size / B;      // 2176

  lstm_kernel<<<dim3(B), dim3(64), 0, stream>>>(x, W_ih, W_hh, b_ih, b_hh,
                                                fc_w, fc_b, out, T, OT);
}